// Round 5
// baseline (106.510 us; speedup 1.0000x reference)
//
#include <hip/hip_runtime.h>
#include <hip/hip_fp16.h>
#include <math.h>

#define NB 16
#define PLEN 1024
#define QLEN 256
#define DIM 256
#define MASKV -10000000.0f

typedef __attribute__((ext_vector_type(8))) short short8;
typedef __attribute__((ext_vector_type(4))) float f32x4;

union u4x16 { unsigned short u[4]; int2 v; };

__device__ inline unsigned short f2bf(float x) {
  unsigned int u = __float_as_uint(x);
  u += 0x7FFF + ((u >> 16) & 1);          // round-to-nearest-even
  return (unsigned short)(u >> 16);
}

// ---------------- k_prep2: one pass over passage/question fp32.
// Produces: Pw = bf16(passage*w_pq), Qb = bf16(question), PbT/QbT (bf16 transposed),
//           sp = passage.w_p, sq = question.w_q
__global__ __launch_bounds__(256) void k_prep2(
    const float* __restrict__ passage, const float* __restrict__ question,
    const float* __restrict__ W,
    unsigned short* __restrict__ Pw, unsigned short* __restrict__ Qb,
    unsigned short* __restrict__ PbT, unsigned short* __restrict__ QbT,
    float* __restrict__ sp, float* __restrict__ sq) {
  int bid = blockIdx.x;
  int t = threadIdx.x;
  __shared__ unsigned short T[64][268];
  int isP = bid < NB * 16;
  int b, r0, R;
  const float* src; unsigned short* cast_out; unsigned short* tdst; float* dots;
  const float* wd; const float* wm;
  if (isP) {
    b = bid >> 4; r0 = (bid & 15) * 64; R = PLEN;
    src = passage + ((size_t)b * PLEN + r0) * DIM;
    cast_out = Pw + ((size_t)b * PLEN + r0) * DIM;
    tdst = PbT + (size_t)b * DIM * PLEN;
    dots = sp + b * PLEN + r0;
    wd = W; wm = W + 2 * DIM;
  } else {
    int bq = bid - NB * 16;
    b = bq >> 2; r0 = (bq & 3) * 64; R = QLEN;
    src = question + ((size_t)b * QLEN + r0) * DIM;
    cast_out = Qb + ((size_t)b * QLEN + r0) * DIM;
    tdst = QbT + (size_t)b * DIM * QLEN;
    dots = sq + b * QLEN + r0;
    wd = W + DIM; wm = nullptr;
  }
  int row = t >> 2, c0 = (t & 3) * 64;
  float s = 0.f;
  for (int i = 0; i < 16; ++i) {
    int d = c0 + i * 4;
    float4 x = *(const float4*)&src[(size_t)row * DIM + d];
    s += x.x * wd[d] + x.y * wd[d + 1] + x.z * wd[d + 2] + x.w * wd[d + 3];
    u4x16 tv;
    tv.u[0] = f2bf(x.x); tv.u[1] = f2bf(x.y); tv.u[2] = f2bf(x.z); tv.u[3] = f2bf(x.w);
    *(int2*)&T[row][d] = tv.v;
    u4x16 ov;
    if (isP) {
      ov.u[0] = f2bf(x.x * wm[d]);     ov.u[1] = f2bf(x.y * wm[d + 1]);
      ov.u[2] = f2bf(x.z * wm[d + 2]); ov.u[3] = f2bf(x.w * wm[d + 3]);
    } else ov = tv;
    *(int2*)&cast_out[(size_t)row * DIM + d] = ov.v;
  }
  s += __shfl_xor(s, 1, 64);
  s += __shfl_xor(s, 2, 64);
  if ((t & 3) == 0) dots[row] = s;
  __syncthreads();
  // transposed write: thread t owns output row d = t (64 p-cols)
  for (int pc = 0; pc < 8; ++pc) {
    union { unsigned short u[8]; int4 v; } o;
    for (int e = 0; e < 8; ++e) o.u[e] = T[pc * 8 + e][t];
    *(int4*)&tdst[(size_t)t * R + r0 + pc * 8] = o.v;
  }
}

// ---------------- k_scoreA: per (b, 64-row p-tile):
//   S = Pw @ Qb^T + sp + sq + b0 (masked)  [full 256-q rows in registers]
//   -> S16 global (fp16, masked -> -inf), col partials CM/CL,
//   -> exact row softmax -> P2Q (global bf16), out1 = P @ QbT^T (fp32)
__global__ __launch_bounds__(256) void k_scoreA(
    const unsigned short* __restrict__ Pw, const unsigned short* __restrict__ Qb,
    const unsigned short* __restrict__ QbT,
    const float* __restrict__ sp, const float* __restrict__ sq,
    const int* __restrict__ pmask, const int* __restrict__ qmask,
    const float* __restrict__ bias,
    __half* __restrict__ S16, float* __restrict__ CM, float* __restrict__ CL,
    unsigned short* __restrict__ P2Q, float* __restrict__ out1) {
  int bid = blockIdx.x;
  int b = bid >> 4;
  int p0 = (bid & 15) * 64;
  int t = threadIdx.x, lane = t & 63, w = t >> 6;
  __shared__ __align__(16) unsigned short As[64][40];
  __shared__ __align__(16) unsigned short Bs[256][40];
  __shared__ __align__(16) unsigned short Pl[64][264];
  __shared__ float redM[4][256];
  __shared__ float redL[4][256];

  // ---- phase 1: score GEMM (64 x 256, K = 256)
  f32x4 acc[16] = {};
  {
    int arow = t >> 2, ac = (t & 3) * 8;
    for (int kt = 0; kt < DIM; kt += 32) {
      __syncthreads();
      *(int4*)&As[arow][ac] = *(const int4*)&Pw[((size_t)b * PLEN + p0 + arow) * DIM + kt + ac];
      for (int c = 0; c < 4; ++c)
        *(int4*)&Bs[t][c * 8] = *(const int4*)&Qb[((size_t)b * QLEN + t) * DIM + kt + c * 8];
      __syncthreads();
      short8 af = *(const short8*)&As[w * 16 + (lane & 15)][(lane >> 4) * 8];
      for (int j = 0; j < 16; ++j) {
        short8 bf = *(const short8*)&Bs[j * 16 + (lane & 15)][(lane >> 4) * 8];
        acc[j] = __builtin_amdgcn_mfma_f32_16x16x32_bf16(af, bf, acc[j], 0, 0, 0);
      }
    }
  }

  // ---- phase 2: epilogue (bias, mask) + S16 store
  float b0 = bias[0];
  int prow[4]; float spv[4]; int pmv[4];
  for (int r = 0; r < 4; ++r) {
    prow[r] = p0 + w * 16 + (lane >> 4) * 4 + r;
    spv[r] = sp[b * PLEN + prow[r]] + b0;
    pmv[r] = pmask[b * PLEN + prow[r]];
  }
  float sqv[16]; int qmv[16];
  for (int j = 0; j < 16; ++j) {
    int q = j * 16 + (lane & 15);
    sqv[j] = sq[b * QLEN + q];
    qmv[j] = qmask[b * QLEN + q];
  }
  for (int j = 0; j < 16; ++j) {
    int q = j * 16 + (lane & 15);
    for (int r = 0; r < 4; ++r) {
      float v = acc[j][r] + spv[r] + sqv[j];
      if (pmv[r] | qmv[j]) v = MASKV;
      acc[j][r] = v;
      S16[((size_t)b * PLEN + prow[r]) * QLEN + q] = __float2half(v);
    }
  }

  // ---- phase 3: column partials over this tile's 64 p
  for (int j = 0; j < 16; ++j) {
    float m = fmaxf(fmaxf(acc[j][0], acc[j][1]), fmaxf(acc[j][2], acc[j][3]));
    m = fmaxf(m, __shfl_xor(m, 16, 64));
    m = fmaxf(m, __shfl_xor(m, 32, 64));
    float s = 0.f;
    for (int r = 0; r < 4; ++r) s += __expf(acc[j][r] - m);
    s += __shfl_xor(s, 16, 64);
    s += __shfl_xor(s, 32, 64);
    if ((lane >> 4) == 0) {
      redM[w][j * 16 + (lane & 15)] = m;
      redL[w][j * 16 + (lane & 15)] = s;
    }
  }
  __syncthreads();
  {
    int q = t;
    float M = fmaxf(fmaxf(redM[0][q], redM[1][q]), fmaxf(redM[2][q], redM[3][q]));
    float L = redL[0][q] * __expf(redM[0][q] - M) + redL[1][q] * __expf(redM[1][q] - M)
            + redL[2][q] * __expf(redM[2][q] - M) + redL[3][q] * __expf(redM[3][q] - M);
    size_t o = ((size_t)b * 16 + (p0 >> 6)) * QLEN + q;
    CM[o] = M; CL[o] = L;
  }

  // ---- phase 4: exact row softmax -> P (bf16) in LDS
  for (int r = 0; r < 4; ++r) {
    float m = acc[0][r];
    for (int j = 1; j < 16; ++j) m = fmaxf(m, acc[j][r]);
    for (int msk = 1; msk <= 8; msk <<= 1) m = fmaxf(m, __shfl_xor(m, msk, 64));
    float l = 0.f;
    for (int j = 0; j < 16; ++j) l += __expf(acc[j][r] - m);
    for (int msk = 1; msk <= 8; msk <<= 1) l += __shfl_xor(l, msk, 64);
    float inv = 1.0f / l;
    int plocal = w * 16 + (lane >> 4) * 4 + r;
    for (int j = 0; j < 16; ++j) {
      float e = (pmv[r] | qmv[j]) ? 0.0f : __expf(acc[j][r] - m) * inv;
      Pl[plocal][j * 16 + (lane & 15)] = f2bf(e);
    }
  }
  __syncthreads();
  // P2Q global (coalesced from LDS)
  for (int k = 0; k < 8; ++k) {
    int idx = t + k * 256;
    int row = idx >> 5, c8 = idx & 31;
    *(int4*)&P2Q[((size_t)b * PLEN + p0 + row) * QLEN + c8 * 8] = *(const int4*)&Pl[row][c8 * 8];
  }

  // ---- phase 5: out1 = P @ QbT^T  (K = 256)
  f32x4 acc2[16] = {};
  for (int kt = 0; kt < QLEN; kt += 32) {
    __syncthreads();
    for (int c = 0; c < 4; ++c)
      *(int4*)&Bs[t][c * 8] = *(const int4*)&QbT[((size_t)b * DIM + t) * QLEN + kt + c * 8];
    __syncthreads();
    short8 af = *(const short8*)&Pl[w * 16 + (lane & 15)][kt + (lane >> 4) * 8];
    for (int j = 0; j < 16; ++j) {
      short8 bf = *(const short8*)&Bs[j * 16 + (lane & 15)][(lane >> 4) * 8];
      acc2[j] = __builtin_amdgcn_mfma_f32_16x16x32_bf16(af, bf, acc2[j], 0, 0, 0);
    }
  }
  for (int j = 0; j < 16; ++j) {
    int d = j * 16 + (lane & 15);
    for (int r = 0; r < 4; ++r)
      out1[((size_t)b * PLEN + prow[r]) * DIM + d] = acc2[j][r];
  }
}

// ---------------- k_colfinish: W2t[b,q,p] = bf16(exp(S16 - M_q) / L_q), via LDS transpose
__global__ void k_colfinish(const __half* __restrict__ S16,
                            const float* __restrict__ CM, const float* __restrict__ CL,
                            unsigned short* __restrict__ W2t) {
  int bid = blockIdx.x;
  int b = bid >> 4, qt = (bid >> 2) & 3, pg = bid & 3;
  int q0 = qt * 64;
  int t = threadIdx.x;
  __shared__ float Mq[64], iLq[64];
  if (t < 64) {
    int q = q0 + t;
    float M = CM[((size_t)b * 16) * QLEN + q];
    for (int tm = 1; tm < 16; ++tm)
      M = fmaxf(M, CM[((size_t)b * 16 + tm) * QLEN + q]);
    float L = 0.f;
    for (int tm = 0; tm < 16; ++tm) {
      size_t o = ((size_t)b * 16 + tm) * QLEN + q;
      L += CL[o] * __expf(CM[o] - M);
    }
    Mq[t] = M; iLq[t] = 1.0f / L;
  }
  __syncthreads();
  __shared__ __align__(16) __half T[64][80];
  int qq = t >> 2, k4 = t & 3;
  for (int c = 0; c < 4; ++c) {
    int p0 = pg * 256 + c * 64;
    for (int k = 0; k < 2; ++k) {
      int idx = t + k * 256;
      int rr = idx >> 3, i4 = idx & 7;
      *(int4*)&T[rr][i4 * 8] =
          *(const int4*)&S16[((size_t)b * PLEN + p0 + rr) * QLEN + q0 + i4 * 8];
    }
    __syncthreads();
    float M = Mq[qq], iL = iLq[qq];
    union { unsigned short u[16]; int4 v[2]; } o;
    for (int e = 0; e < 16; ++e) {
      int pp = k4 * 16 + e;
      float s = __half2float(T[pp][qq]);
      o.u[e] = f2bf(__expf(s - M) * iL);
    }
    unsigned short* dst = W2t + ((size_t)b * QLEN + q0 + qq) * PLEN + p0 + k4 * 16;
    *(int4*)dst = o.v[0];
    *(int4*)(dst + 8) = o.v[1];
    __syncthreads();
  }
}

// ---------------- k_gemm_qatt: QATTt[b,d,q] = PbT @ W2t^T  (K = PLEN)
__global__ __launch_bounds__(256) void k_gemm_qatt(
    const unsigned short* __restrict__ PbT, const unsigned short* __restrict__ W2t,
    unsigned short* __restrict__ QATTt) {
  int bid = blockIdx.x;
  int b = bid >> 4;
  int tm = (bid >> 2) & 3;
  int tn = bid & 3;
  const unsigned short* A  = PbT + ((size_t)b * DIM + tm * 64) * PLEN;
  const unsigned short* Bm = W2t + ((size_t)b * QLEN + tn * 64) * PLEN;
  __shared__ __align__(16) unsigned short As[64][72];
  __shared__ __align__(16) unsigned short Bs[64][72];
  int t = threadIdx.x, lane = t & 63, wid = t >> 6;
  int wm = wid >> 1, wn = wid & 1;
  f32x4 acc[2][2] = {};
  int srow = t >> 3, sc = (t & 7) * 8;
  for (int kt = 0; kt < PLEN; kt += 64) {
    __syncthreads();
    for (int i = 0; i < 2; ++i) {
      int r = srow + i * 32;
      *(int4*)&As[r][sc] = *(const int4*)&A[(size_t)r * PLEN + kt + sc];
      *(int4*)&Bs[r][sc] = *(const int4*)&Bm[(size_t)r * PLEN + kt + sc];
    }
    __syncthreads();
    for (int kk = 0; kk < 64; kk += 32) {
      short8 af[2], bf[2];
      for (int i = 0; i < 2; ++i)
        af[i] = *(const short8*)&As[wm * 32 + i * 16 + (lane & 15)][kk + (lane >> 4) * 8];
      for (int j = 0; j < 2; ++j)
        bf[j] = *(const short8*)&Bs[wn * 32 + j * 16 + (lane & 15)][kk + (lane >> 4) * 8];
      for (int i = 0; i < 2; ++i)
        for (int j = 0; j < 2; ++j)
          acc[i][j] = __builtin_amdgcn_mfma_f32_16x16x32_bf16(af[i], bf[j], acc[i][j], 0, 0, 0);
    }
  }
  int d0 = tm * 64 + wm * 32, q0 = tn * 64 + wn * 32;
  for (int i = 0; i < 2; ++i)
    for (int r = 0; r < 4; ++r) {
      int d = d0 + i * 16 + (lane >> 4) * 4 + r;
      for (int j = 0; j < 2; ++j) {
        int q = q0 + j * 16 + (lane & 15);
        QATTt[((size_t)b * DIM + d) * QLEN + q] = f2bf(acc[i][j][r]);
      }
    }
}

// ---------------- k_gemm_final2: out2 = P2Q @ QATTt^T
__global__ __launch_bounds__(256) void k_gemm_final2(
    const unsigned short* __restrict__ P2Q, const unsigned short* __restrict__ QATTt,
    float* __restrict__ out2) {
  int bid = blockIdx.x;
  int b = bid >> 4;
  int tm = (bid >> 1) & 7;
  int tn = bid & 1;
  const unsigned short* A  = P2Q + ((size_t)b * PLEN + tm * 128) * QLEN;
  const unsigned short* B2 = QATTt + ((size_t)b * DIM + tn * 128) * QLEN;
  __shared__ __align__(16) unsigned short As[128][40];
  __shared__ __align__(16) unsigned short Bc[128][40];
  int t = threadIdx.x, lane = t & 63, wid = t >> 6;
  int wm = wid >> 1, wn = wid & 1;
  f32x4 acc[4][4] = {};
  int srow = t >> 2, sc = (t & 3) * 8;
  for (int kt = 0; kt < QLEN; kt += 32) {
    __syncthreads();
    for (int i = 0; i < 2; ++i) {
      int r = srow + i * 64;
      *(int4*)&As[r][sc] = *(const int4*)&A[(size_t)r * QLEN + kt + sc];
      *(int4*)&Bc[r][sc] = *(const int4*)&B2[(size_t)r * QLEN + kt + sc];
    }
    __syncthreads();
    short8 af[4], bc[4];
    for (int i = 0; i < 4; ++i)
      af[i] = *(const short8*)&As[wm * 64 + i * 16 + (lane & 15)][(lane >> 4) * 8];
    for (int j = 0; j < 4; ++j)
      bc[j] = *(const short8*)&Bc[wn * 64 + j * 16 + (lane & 15)][(lane >> 4) * 8];
    for (int i = 0; i < 4; ++i)
      for (int j = 0; j < 4; ++j)
        acc[i][j] = __builtin_amdgcn_mfma_f32_16x16x32_bf16(af[i], bc[j], acc[i][j], 0, 0, 0);
  }
  int p0 = tm * 128 + wm * 64, d0 = tn * 128 + wn * 64;
  for (int i = 0; i < 4; ++i)
    for (int r = 0; r < 4; ++r) {
      int p = p0 + i * 16 + (lane >> 4) * 4 + r;
      size_t rowo = ((size_t)b * PLEN + p) * DIM;
      for (int j = 0; j < 4; ++j) {
        int d = d0 + j * 16 + (lane & 15);
        out2[rowo + d] = acc[i][j][r];
      }
    }
}

extern "C" void kernel_launch(void* const* d_in, const int* in_sizes, int n_in,
                              void* d_out, int out_size, void* d_ws, size_t ws_size,
                              hipStream_t stream) {
  const float* passage  = (const float*)d_in[0];
  const float* question = (const float*)d_in[1];
  const int*   pmask    = (const int*)d_in[2];
  const int*   qmask    = (const int*)d_in[3];
  const float* W        = (const float*)d_in[4];
  const float* bias     = (const float*)d_in[5];
  float* out = (float*)d_out;

  const size_t NS = (size_t)NB * PLEN * QLEN;    // 4,194,304
  const size_t NQ = (size_t)NB * QLEN * DIM;     // 1,048,576
  char* w = (char*)d_ws;
  __half* S16 = (__half*)w;                 w += NS * 2;
  unsigned short* Pw   = (unsigned short*)w; w += NS * 2;
  unsigned short* Qb   = (unsigned short*)w; w += NQ * 2;
  unsigned short* PbT  = (unsigned short*)w; w += NS * 2;
  unsigned short* QbT  = (unsigned short*)w; w += NQ * 2;
  unsigned short* P2Q  = (unsigned short*)w; w += NS * 2;
  unsigned short* W2t  = (unsigned short*)w; w += NS * 2;
  unsigned short* QATTt = (unsigned short*)w; w += NQ * 2;
  float* CM = (float*)w;                    w += (size_t)NB * 16 * QLEN * 4;
  float* CL = (float*)w;                    w += (size_t)NB * 16 * QLEN * 4;
  float* sp = (float*)w;                    w += (size_t)NB * PLEN * 4;
  float* sq = (float*)w;

  float* out1 = out;
  float* out2 = out + (size_t)NB * PLEN * DIM;

  k_prep2<<<dim3(NB * 16 + NB * 4), dim3(256), 0, stream>>>(
      passage, question, W, Pw, Qb, PbT, QbT, sp, sq);
  k_scoreA<<<dim3(NB * 16), dim3(256), 0, stream>>>(
      Pw, Qb, QbT, sp, sq, pmask, qmask, bias, S16, CM, CL, P2Q, out1);
  k_colfinish<<<dim3(NB * 16), dim3(256), 0, stream>>>(
      S16, CM, CL, W2t);
  k_gemm_qatt<<<dim3(NB * 16), dim3(256), 0, stream>>>(
      PbT, W2t, QATTt);
  k_gemm_final2<<<dim3(NB * 16), dim3(256), 0, stream>>>(
      P2Q, QATTt, out2);
}

// Round 6
// 84.907 us; speedup vs baseline: 1.2544x; 1.2544x over previous
//
#include <hip/hip_runtime.h>
#include <hip/hip_fp16.h>
#include <math.h>

#define NB 16
#define PLEN 1024
#define QLEN 256
#define DIM 256
#define MASKV -10000000.0f

typedef __attribute__((ext_vector_type(8))) short short8;
typedef __attribute__((ext_vector_type(4))) float f32x4;

union u4x16 { unsigned short u[4]; int2 v; };
union u8x16 { unsigned short u[8]; int4 v; };

__device__ inline unsigned short f2bf(float x) {
  unsigned int u = __float_as_uint(x);
  u += 0x7FFF + ((u >> 16) & 1);          // round-to-nearest-even
  return (unsigned short)(u >> 16);
}

// ---------------- k_prep2: one pass over passage/question fp32.
__global__ __launch_bounds__(256) void k_prep2(
    const float* __restrict__ passage, const float* __restrict__ question,
    const float* __restrict__ W,
    unsigned short* __restrict__ Pw, unsigned short* __restrict__ Qb,
    unsigned short* __restrict__ PbT, unsigned short* __restrict__ QbT,
    float* __restrict__ sp, float* __restrict__ sq) {
  int bid = blockIdx.x;
  int t = threadIdx.x;
  __shared__ unsigned short T[64][268];
  int isP = bid < NB * 16;
  int b, r0, R;
  const float* src; unsigned short* cast_out; unsigned short* tdst; float* dots;
  const float* wd; const float* wm;
  if (isP) {
    b = bid >> 4; r0 = (bid & 15) * 64; R = PLEN;
    src = passage + ((size_t)b * PLEN + r0) * DIM;
    cast_out = Pw + ((size_t)b * PLEN + r0) * DIM;
    tdst = PbT + (size_t)b * DIM * PLEN;
    dots = sp + b * PLEN + r0;
    wd = W; wm = W + 2 * DIM;
  } else {
    int bq = bid - NB * 16;
    b = bq >> 2; r0 = (bq & 3) * 64; R = QLEN;
    src = question + ((size_t)b * QLEN + r0) * DIM;
    cast_out = Qb + ((size_t)b * QLEN + r0) * DIM;
    tdst = QbT + (size_t)b * DIM * QLEN;
    dots = sq + b * QLEN + r0;
    wd = W + DIM; wm = nullptr;
  }
  int row = t >> 2, c0 = (t & 3) * 64;
  float s = 0.f;
  for (int i = 0; i < 16; ++i) {
    int d = c0 + i * 4;
    float4 x = *(const float4*)&src[(size_t)row * DIM + d];
    s += x.x * wd[d] + x.y * wd[d + 1] + x.z * wd[d + 2] + x.w * wd[d + 3];
    u4x16 tv;
    tv.u[0] = f2bf(x.x); tv.u[1] = f2bf(x.y); tv.u[2] = f2bf(x.z); tv.u[3] = f2bf(x.w);
    *(int2*)&T[row][d] = tv.v;
    u4x16 ov;
    if (isP) {
      ov.u[0] = f2bf(x.x * wm[d]);     ov.u[1] = f2bf(x.y * wm[d + 1]);
      ov.u[2] = f2bf(x.z * wm[d + 2]); ov.u[3] = f2bf(x.w * wm[d + 3]);
    } else ov = tv;
    *(int2*)&cast_out[(size_t)row * DIM + d] = ov.v;
  }
  s += __shfl_xor(s, 1, 64);
  s += __shfl_xor(s, 2, 64);
  if ((t & 3) == 0) dots[row] = s;
  __syncthreads();
  for (int pc = 0; pc < 8; ++pc) {
    u8x16 o;
    for (int e = 0; e < 8; ++e) o.u[e] = T[pc * 8 + e][t];
    *(int4*)&tdst[(size_t)t * R + r0 + pc * 8] = o.v;
  }
}

// ---------------- k_scoreA (512 thr, 8 waves): score GEMM + masks + S16 + col partials
//                  + exact row softmax -> P2Q + out1 GEMM
__global__ __launch_bounds__(512) void k_scoreA(
    const unsigned short* __restrict__ Pw, const unsigned short* __restrict__ Qb,
    const unsigned short* __restrict__ QbT,
    const float* __restrict__ sp, const float* __restrict__ sq,
    const int* __restrict__ pmask, const int* __restrict__ qmask,
    const float* __restrict__ bias,
    __half* __restrict__ S16, float* __restrict__ CM, float* __restrict__ CL,
    unsigned short* __restrict__ P2Q, float* __restrict__ out1) {
  int bid = blockIdx.x;
  int b = bid >> 4;
  int p0 = (bid & 15) * 64;
  int t = threadIdx.x, lane = t & 63, wv = t >> 6;   // 8 waves
  int s = wv >> 1, h = wv & 1;                        // row-strip 0..3, q-half 0..1
  __shared__ __align__(16) unsigned short As[64][40];
  __shared__ __align__(16) unsigned short Bs[256][40];
  __shared__ __align__(16) unsigned short Pl[64][264];
  __shared__ float redM[4][256], redL[4][256];
  __shared__ float rowM[64][2], rowL[64][2];

  // ---- phase 1: score GEMM (64 x 256, K = 256); wave = 16 rows x 128 q
  f32x4 acc[8] = {};
  for (int kt = 0; kt < DIM; kt += 32) {
    __syncthreads();
    if (t < 256) {
      for (int c = 0; c < 4; ++c)
        *(int4*)&Bs[t][c * 8] = *(const int4*)&Qb[((size_t)b * QLEN + t) * DIM + kt + c * 8];
    } else {
      int t2 = t - 256;
      *(int4*)&As[t2 >> 2][(t2 & 3) * 8] =
          *(const int4*)&Pw[((size_t)b * PLEN + p0 + (t2 >> 2)) * DIM + kt + (t2 & 3) * 8];
    }
    __syncthreads();
    short8 af = *(const short8*)&As[s * 16 + (lane & 15)][(lane >> 4) * 8];
    for (int j = 0; j < 8; ++j) {
      short8 bf = *(const short8*)&Bs[h * 128 + j * 16 + (lane & 15)][(lane >> 4) * 8];
      acc[j] = __builtin_amdgcn_mfma_f32_16x16x32_bf16(af, bf, acc[j], 0, 0, 0);
    }
  }

  // ---- phase 2: bias + mask epilogue + S16 store
  float b0 = bias[0];
  int prow[4]; float spv[4]; int pmv[4];
  for (int r = 0; r < 4; ++r) {
    prow[r] = p0 + s * 16 + (lane >> 4) * 4 + r;
    spv[r] = sp[b * PLEN + prow[r]] + b0;
    pmv[r] = pmask[b * PLEN + prow[r]];
  }
  float sqv[8]; int qmv[8];
  for (int j = 0; j < 8; ++j) {
    int q = h * 128 + j * 16 + (lane & 15);
    sqv[j] = sq[b * QLEN + q];
    qmv[j] = qmask[b * QLEN + q];
  }
  for (int j = 0; j < 8; ++j) {
    int q = h * 128 + j * 16 + (lane & 15);
    for (int r = 0; r < 4; ++r) {
      float v = acc[j][r] + spv[r] + sqv[j];
      if (pmv[r] | qmv[j]) v = MASKV;
      acc[j][r] = v;
      S16[((size_t)b * PLEN + prow[r]) * QLEN + q] = __float2half(v);
    }
  }

  // ---- phase 3a: per-strip column partials + per-row/half partials
  for (int j = 0; j < 8; ++j) {
    float m = fmaxf(fmaxf(acc[j][0], acc[j][1]), fmaxf(acc[j][2], acc[j][3]));
    m = fmaxf(m, __shfl_xor(m, 16, 64));
    m = fmaxf(m, __shfl_xor(m, 32, 64));
    float e = 0.f;
    for (int r = 0; r < 4; ++r) e += __expf(acc[j][r] - m);
    e += __shfl_xor(e, 16, 64);
    e += __shfl_xor(e, 32, 64);
    if ((lane >> 4) == 0) {
      redM[s][h * 128 + j * 16 + (lane & 15)] = m;
      redL[s][h * 128 + j * 16 + (lane & 15)] = e;
    }
  }
  for (int r = 0; r < 4; ++r) {
    int rl = s * 16 + (lane >> 4) * 4 + r;
    float m = acc[0][r];
    for (int j = 1; j < 8; ++j) m = fmaxf(m, acc[j][r]);
    for (int msk = 1; msk <= 8; msk <<= 1) m = fmaxf(m, __shfl_xor(m, msk, 64));
    float l = 0.f;
    for (int j = 0; j < 8; ++j) l += __expf(acc[j][r] - m);
    for (int msk = 1; msk <= 8; msk <<= 1) l += __shfl_xor(l, msk, 64);
    if ((lane & 15) == 0) { rowM[rl][h] = m; rowL[rl][h] = l; }
  }
  __syncthreads();

  // ---- phase 3b: CM/CL store (combine 4 strips)
  if (t < 256) {
    int q = t;
    float M = fmaxf(fmaxf(redM[0][q], redM[1][q]), fmaxf(redM[2][q], redM[3][q]));
    float L = redL[0][q] * __expf(redM[0][q] - M) + redL[1][q] * __expf(redM[1][q] - M)
            + redL[2][q] * __expf(redM[2][q] - M) + redL[3][q] * __expf(redM[3][q] - M);
    size_t o = ((size_t)b * 16 + (p0 >> 6)) * QLEN + q;
    CM[o] = M; CL[o] = L;
  }

  // ---- phase 4: exact row softmax (combine 2 halves) -> Pl (bf16)
  for (int r = 0; r < 4; ++r) {
    int rl = s * 16 + (lane >> 4) * 4 + r;
    float m0 = rowM[rl][0], m1 = rowM[rl][1];
    float m = fmaxf(m0, m1);
    float l = rowL[rl][0] * __expf(m0 - m) + rowL[rl][1] * __expf(m1 - m);
    float inv = 1.0f / l;
    for (int j = 0; j < 8; ++j) {
      float e = (pmv[r] | qmv[j]) ? 0.0f : __expf(acc[j][r] - m) * inv;
      Pl[rl][h * 128 + j * 16 + (lane & 15)] = f2bf(e);
    }
  }
  __syncthreads();

  // ---- P2Q global store (vectorized from LDS)
  for (int k = 0; k < 4; ++k) {
    int g = t + k * 512;
    int row = g >> 5, c8 = g & 31;
    *(int4*)&P2Q[((size_t)b * PLEN + p0 + row) * QLEN + c8 * 8] = *(const int4*)&Pl[row][c8 * 8];
  }

  // ---- phase 5: out1 = P @ QbT^T  (K = 256); wave = 16 rows x 128 d
  f32x4 acc2[8] = {};
  for (int kt = 0; kt < QLEN; kt += 32) {
    __syncthreads();
    {
      int row = t >> 1, c = (t & 1) * 16;
      *(int4*)&Bs[row][c]     = *(const int4*)&QbT[((size_t)b * DIM + row) * QLEN + kt + c];
      *(int4*)&Bs[row][c + 8] = *(const int4*)&QbT[((size_t)b * DIM + row) * QLEN + kt + c + 8];
    }
    __syncthreads();
    short8 af = *(const short8*)&Pl[s * 16 + (lane & 15)][kt + (lane >> 4) * 8];
    for (int j = 0; j < 8; ++j) {
      short8 bf = *(const short8*)&Bs[h * 128 + j * 16 + (lane & 15)][(lane >> 4) * 8];
      acc2[j] = __builtin_amdgcn_mfma_f32_16x16x32_bf16(af, bf, acc2[j], 0, 0, 0);
    }
  }
  for (int j = 0; j < 8; ++j) {
    int d = h * 128 + j * 16 + (lane & 15);
    for (int r = 0; r < 4; ++r)
      out1[((size_t)b * PLEN + prow[r]) * DIM + d] = acc2[j][r];
  }
}

// ---------------- k_colfinish: W2t[b,q,p] = bf16(exp(S16 - M_q)/L_q); 64q x 64p per block
__global__ __launch_bounds__(256) void k_colfinish(
    const __half* __restrict__ S16,
    const float* __restrict__ CM, const float* __restrict__ CL,
    unsigned short* __restrict__ W2t) {
  int bid = blockIdx.x;
  int b = bid >> 6, qt = (bid >> 4) & 3, pg = bid & 15;
  int q0 = qt * 64, p0 = pg * 64;
  int t = threadIdx.x;
  __shared__ float Mq[64], iLq[64];
  if (t < 64) {
    int q = q0 + t;
    float M = CM[((size_t)b * 16) * QLEN + q];
    for (int tm = 1; tm < 16; ++tm)
      M = fmaxf(M, CM[((size_t)b * 16 + tm) * QLEN + q]);
    float L = 0.f;
    for (int tm = 0; tm < 16; ++tm) {
      size_t o = ((size_t)b * 16 + tm) * QLEN + q;
      L += CL[o] * __expf(CM[o] - M);
    }
    Mq[t] = M; iLq[t] = 1.0f / L;
  }
  __shared__ __align__(16) __half T[64][80];
  for (int k = 0; k < 2; ++k) {
    int idx = t + k * 256;
    int rr = idx >> 3, i4 = idx & 7;
    *(int4*)&T[rr][i4 * 8] =
        *(const int4*)&S16[((size_t)b * PLEN + p0 + rr) * QLEN + q0 + i4 * 8];
  }
  __syncthreads();
  int qq = t >> 2, k4 = t & 3;
  float M = Mq[qq], iL = iLq[qq];
  union { unsigned short u[16]; int4 v[2]; } o;
  for (int e = 0; e < 16; ++e) {
    int pp = k4 * 16 + e;
    float sv = __half2float(T[pp][qq]);
    o.u[e] = f2bf(__expf(sv - M) * iL);
  }
  unsigned short* dst = W2t + ((size_t)b * QLEN + q0 + qq) * PLEN + p0 + k4 * 16;
  *(int4*)dst = o.v[0];
  *(int4*)(dst + 8) = o.v[1];
}

// ---------------- k_gemm_qatt: QATTf[kh][b,d,q] = PbT @ W2t^T over K-half (fp32 partial)
__global__ __launch_bounds__(256) void k_gemm_qatt(
    const unsigned short* __restrict__ PbT, const unsigned short* __restrict__ W2t,
    float* __restrict__ QATTf) {
  int bid = blockIdx.x;
  int kh = bid >> 8;
  int r8 = bid & 255;
  int b = r8 >> 4;
  int tm = (r8 >> 2) & 3;
  int tn = r8 & 3;
  const unsigned short* A  = PbT + ((size_t)b * DIM + tm * 64) * PLEN;
  const unsigned short* Bm = W2t + ((size_t)b * QLEN + tn * 64) * PLEN;
  float* outp = QATTf + (size_t)kh * NB * DIM * QLEN;
  __shared__ __align__(16) unsigned short As[64][72];
  __shared__ __align__(16) unsigned short Bs[64][72];
  int t = threadIdx.x, lane = t & 63, wid = t >> 6;
  int wm = wid >> 1, wn = wid & 1;
  f32x4 acc[2][2] = {};
  int srow = t >> 3, sc = (t & 7) * 8;
  for (int kt = kh * 512; kt < kh * 512 + 512; kt += 64) {
    __syncthreads();
    for (int i = 0; i < 2; ++i) {
      int r = srow + i * 32;
      *(int4*)&As[r][sc] = *(const int4*)&A[(size_t)r * PLEN + kt + sc];
      *(int4*)&Bs[r][sc] = *(const int4*)&Bm[(size_t)r * PLEN + kt + sc];
    }
    __syncthreads();
    for (int kk = 0; kk < 64; kk += 32) {
      short8 af[2], bf[2];
      for (int i = 0; i < 2; ++i)
        af[i] = *(const short8*)&As[wm * 32 + i * 16 + (lane & 15)][kk + (lane >> 4) * 8];
      for (int j = 0; j < 2; ++j)
        bf[j] = *(const short8*)&Bs[wn * 32 + j * 16 + (lane & 15)][kk + (lane >> 4) * 8];
      for (int i = 0; i < 2; ++i)
        for (int j = 0; j < 2; ++j)
          acc[i][j] = __builtin_amdgcn_mfma_f32_16x16x32_bf16(af[i], bf[j], acc[i][j], 0, 0, 0);
    }
  }
  int d0 = tm * 64 + wm * 32, q0 = tn * 64 + wn * 32;
  for (int i = 0; i < 2; ++i)
    for (int r = 0; r < 4; ++r) {
      int d = d0 + i * 16 + (lane >> 4) * 4 + r;
      for (int j = 0; j < 2; ++j) {
        int q = q0 + j * 16 + (lane & 15);
        outp[((size_t)b * DIM + d) * QLEN + q] = acc[i][j][r];
      }
    }
}

// ---------------- k_gemm_final2: out2 = P2Q @ (QATTf0+QATTf1)^T; 64p x 128d per block
__global__ __launch_bounds__(256) void k_gemm_final2(
    const unsigned short* __restrict__ P2Q, const float* __restrict__ QATTf,
    float* __restrict__ out2) {
  int bid = blockIdx.x;
  int b = bid >> 5;
  int t5 = bid & 31;
  int tm = t5 >> 1;            // 16 p-tiles of 64
  int tn = t5 & 1;             // 2 d-tiles of 128
  int p0 = tm * 64, d0 = tn * 128;
  const float* Q0 = QATTf;
  const float* Q1 = QATTf + (size_t)NB * DIM * QLEN;
  __shared__ __align__(16) unsigned short As[64][40];
  __shared__ __align__(16) unsigned short Bc[128][40];
  int t = threadIdx.x, lane = t & 63, wv = t >> 6;   // 4 waves; wave = 16 rows x 128 d
  f32x4 acc[8] = {};
  for (int kt = 0; kt < QLEN; kt += 32) {
    __syncthreads();
    {
      int row = t >> 2, c = (t & 3) * 8;
      *(int4*)&As[row][c] = *(const int4*)&P2Q[((size_t)b * PLEN + p0 + row) * QLEN + kt + c];
    }
    for (int k = 0; k < 2; ++k) {
      int pos = t + k * 256;
      int row = pos >> 2, c = (pos & 3) * 8;
      const float* s0 = Q0 + ((size_t)b * DIM + d0 + row) * QLEN + kt + c;
      const float* s1 = Q1 + ((size_t)b * DIM + d0 + row) * QLEN + kt + c;
      float4 a0 = *(const float4*)s0, a1 = *(const float4*)(s0 + 4);
      float4 b0v = *(const float4*)s1, b1v = *(const float4*)(s1 + 4);
      u8x16 o;
      o.u[0] = f2bf(a0.x + b0v.x); o.u[1] = f2bf(a0.y + b0v.y);
      o.u[2] = f2bf(a0.z + b0v.z); o.u[3] = f2bf(a0.w + b0v.w);
      o.u[4] = f2bf(a1.x + b1v.x); o.u[5] = f2bf(a1.y + b1v.y);
      o.u[6] = f2bf(a1.z + b1v.z); o.u[7] = f2bf(a1.w + b1v.w);
      *(int4*)&Bc[row][c] = o.v;
    }
    __syncthreads();
    short8 af = *(const short8*)&As[wv * 16 + (lane & 15)][(lane >> 4) * 8];
    for (int j = 0; j < 8; ++j) {
      short8 bf = *(const short8*)&Bc[j * 16 + (lane & 15)][(lane >> 4) * 8];
      acc[j] = __builtin_amdgcn_mfma_f32_16x16x32_bf16(af, bf, acc[j], 0, 0, 0);
    }
  }
  for (int j = 0; j < 8; ++j) {
    int d = d0 + j * 16 + (lane & 15);
    for (int r = 0; r < 4; ++r) {
      int p = p0 + wv * 16 + (lane >> 4) * 4 + r;
      out2[((size_t)b * PLEN + p) * DIM + d] = acc[j][r];
    }
  }
}

extern "C" void kernel_launch(void* const* d_in, const int* in_sizes, int n_in,
                              void* d_out, int out_size, void* d_ws, size_t ws_size,
                              hipStream_t stream) {
  const float* passage  = (const float*)d_in[0];
  const float* question = (const float*)d_in[1];
  const int*   pmask    = (const int*)d_in[2];
  const int*   qmask    = (const int*)d_in[3];
  const float* W        = (const float*)d_in[4];
  const float* bias     = (const float*)d_in[5];
  float* out = (float*)d_out;

  const size_t NS = (size_t)NB * PLEN * QLEN;    // 4,194,304
  const size_t NQ = (size_t)NB * QLEN * DIM;     // 1,048,576
  char* w = (char*)d_ws;
  __half* S16 = (__half*)w;                  w += NS * 2;
  unsigned short* Pw   = (unsigned short*)w; w += NS * 2;
  unsigned short* Qb   = (unsigned short*)w; w += NQ * 2;
  unsigned short* PbT  = (unsigned short*)w; w += NS * 2;
  unsigned short* QbT  = (unsigned short*)w; w += NQ * 2;
  unsigned short* P2Q  = (unsigned short*)w; w += NS * 2;
  unsigned short* W2t  = (unsigned short*)w; w += NS * 2;
  float* QATTf = (float*)w;                  w += 2 * NQ * 4;   // two fp32 K-halves
  float* CM = (float*)w;                     w += (size_t)NB * 16 * QLEN * 4;
  float* CL = (float*)w;                     w += (size_t)NB * 16 * QLEN * 4;
  float* sp = (float*)w;                     w += (size_t)NB * PLEN * 4;
  float* sq = (float*)w;

  float* out1 = out;
  float* out2 = out + (size_t)NB * PLEN * DIM;

  k_prep2<<<dim3(NB * 16 + NB * 4), dim3(256), 0, stream>>>(
      passage, question, W, Pw, Qb, PbT, QbT, sp, sq);
  k_scoreA<<<dim3(NB * 16), dim3(512), 0, stream>>>(
      Pw, Qb, QbT, sp, sq, pmask, qmask, bias, S16, CM, CL, P2Q, out1);
  k_colfinish<<<dim3(NB * 4 * 16), dim3(256), 0, stream>>>(
      S16, CM, CL, W2t);
  k_gemm_qatt<<<dim3(2 * NB * 16), dim3(256), 0, stream>>>(
      PbT, W2t, QATTf);
  k_gemm_final2<<<dim3(NB * 16 * 2), dim3(256), 0, stream>>>(
      P2Q, QATTf, out2);
}